// Round 3
// baseline (1957.489 us; speedup 1.0000x reference)
//
#include <hip/hip_runtime.h>
#include <hip/hip_bf16.h>

typedef __hip_bfloat16 bf16;
typedef unsigned short u16;
typedef unsigned int u32;

#define NROWS (8*128*128)   // 131072 spatial positions
#define DIM 256
#define QKVN 768
#define HD 32
#define SEQ 256             // stripe sequence length = sw(2) * 128

__device__ __forceinline__ float b2f_bits(u16 u) {
    union { float f; u32 i; } x; x.i = ((u32)u) << 16; return x.f;
}
__device__ __forceinline__ u16 f2b_bits(float f) {
    bf16 h = __float2bfloat16(f);
    return *reinterpret_cast<u16*>(&h);
}
__device__ __forceinline__ u32 pack2(float a, float b) {
    return ((u32)f2b_bits(b) << 16) | (u32)f2b_bits(a);
}
// dual-dtype scalar load: input tensors are f32 (reference dtype); bf16 fallback kept
__device__ __forceinline__ float dload(const void* p, size_t i, bool f32) {
    if (f32) return reinterpret_cast<const float*>(p)[i];
    return b2f_bits(reinterpret_cast<const u16*>(p)[i]);
}
// gamma == ones: f32 word = 0x3F800000, packed bf16 pair = 0x3F803F80
__device__ __forceinline__ bool probe_is_f32(const void* probe) {
    return *reinterpret_cast<const u32*>(probe) == 0x3F800000u;
}
// load 8 consecutive bf16 (16B) -> 8 floats
__device__ __forceinline__ void load8f(const bf16* p, float* d) {
    uint4 w = *reinterpret_cast<const uint4*>(p);
    d[0] = b2f_bits((u16)(w.x & 0xffff)); d[1] = b2f_bits((u16)(w.x >> 16));
    d[2] = b2f_bits((u16)(w.y & 0xffff)); d[3] = b2f_bits((u16)(w.y >> 16));
    d[4] = b2f_bits((u16)(w.z & 0xffff)); d[5] = b2f_bits((u16)(w.z >> 16));
    d[6] = b2f_bits((u16)(w.w & 0xffff)); d[7] = b2f_bits((u16)(w.w >> 16));
}

// ---------------- LayerNorm: one block (256 thr) per row ----------------
__global__ __launch_bounds__(256) void ln_kernel(
        const void* __restrict__ x, const void* __restrict__ gamma,
        const void* __restrict__ beta, bf16* __restrict__ xn, size_t x_off) {
    __shared__ float red[8];
    const bool f32 = probe_is_f32(gamma);
    const int row = blockIdx.x;
    const int t = threadIdx.x;
    const size_t base = x_off + (size_t)row * DIM;
    float v = dload(x, base + t, f32);

    float s = v;
    #pragma unroll
    for (int off = 32; off > 0; off >>= 1) s += __shfl_down(s, off, 64);
    const int wave = t >> 6, lane = t & 63;
    if (lane == 0) red[wave] = s;
    __syncthreads();
    if (t == 0) red[4] = (red[0] + red[1] + red[2] + red[3]) * (1.0f / DIM);
    __syncthreads();
    const float mean = red[4];

    const float d = v - mean;
    s = d * d;
    #pragma unroll
    for (int off = 32; off > 0; off >>= 1) s += __shfl_down(s, off, 64);
    if (lane == 0) red[wave] = s;
    __syncthreads();
    if (t == 0) red[5] = rsqrtf((red[0] + red[1] + red[2] + red[3]) * (1.0f / DIM) + 1e-5f);
    __syncthreads();
    const float rstd = red[5];

    const float g = dload(gamma, t, f32), bb = dload(beta, t, f32);
    xn[(size_t)row * DIM + t] = __float2bfloat16(d * rstd * g + bb);
}

// ---------------- Tiled GEMM (fp32 accumulate, bf16 A, dual-dtype B) -------
// C[M,N] = A[M,K] @ B[K,N] + bias[N] (+ resid[M,N]); all row-major.
// out_f32: store f32 (final output) vs packed bf16 (internal tensors).
#define BM 64
#define BN 64
#define BK 16
__global__ __launch_bounds__(256) void gemm_kernel(
        const bf16* __restrict__ A, const void* __restrict__ Bm,
        const void* __restrict__ bias, const void* __restrict__ resid,
        size_t resid_off, const void* __restrict__ probe,
        void* __restrict__ Cout, int M, int N, int K, int out_f32) {
    __shared__ float As[BM][BK + 1];
    __shared__ float Bs[BK][BN];

    const bool f32 = probe_is_f32(probe);
    const int tid = threadIdx.x;
    const int row0 = blockIdx.y * BM;
    const int col0 = blockIdx.x * BN;
    const int ty = tid >> 4, tx = tid & 15;

    const int ar = tid >> 2, ac = (tid & 3) * 4;   // A: 64 rows x 16 cols
    const int br = tid >> 4, bc = (tid & 15) * 4;  // B: 16 rows x 64 cols

    float acc[4][4] = {};

    for (int k0 = 0; k0 < K; k0 += BK) {
        __syncthreads();
        {
            // A tile (bf16 always): 4 bf16 per thread (uint2)
            uint2 w = *reinterpret_cast<const uint2*>(A + (size_t)(row0 + ar) * K + k0 + ac);
            As[ar][ac + 0] = b2f_bits((u16)(w.x & 0xffff));
            As[ar][ac + 1] = b2f_bits((u16)(w.x >> 16));
            As[ar][ac + 2] = b2f_bits((u16)(w.y & 0xffff));
            As[ar][ac + 3] = b2f_bits((u16)(w.y >> 16));
            // B tile (dual dtype, scalar loads)
            const size_t bbase = (size_t)(k0 + br) * N + col0 + bc;
            #pragma unroll
            for (int j = 0; j < 4; j++) Bs[br][bc + j] = dload(Bm, bbase + j, f32);
        }
        __syncthreads();
        #pragma unroll
        for (int ky = 0; ky < BK; ky++) {
            float a[4], b[4];
            #pragma unroll
            for (int i = 0; i < 4; i++) a[i] = As[ty * 4 + i][ky];
            #pragma unroll
            for (int j = 0; j < 4; j++) b[j] = Bs[ky][tx * 4 + j];
            #pragma unroll
            for (int i = 0; i < 4; i++)
                #pragma unroll
                for (int j = 0; j < 4; j++)
                    acc[i][j] += a[i] * b[j];
        }
    }

    #pragma unroll
    for (int i = 0; i < 4; i++) {
        const int r = row0 + ty * 4 + i;
        const int c = col0 + tx * 4;
        float o[4];
        #pragma unroll
        for (int j = 0; j < 4; j++) {
            o[j] = acc[i][j] + dload(bias, c + j, f32);
            if (resid) o[j] += dload(resid, resid_off + (size_t)r * N + c + j, f32);
        }
        if (out_f32) {
            float4 w = make_float4(o[0], o[1], o[2], o[3]);
            *reinterpret_cast<float4*>((float*)Cout + (size_t)r * N + c) = w;
        } else {
            uint2 w;
            w.x = pack2(o[0], o[1]);
            w.y = pack2(o[2], o[3]);
            *reinterpret_cast<uint2*>((bf16*)Cout + (size_t)r * N + c) = w;
        }
    }
}

// ---------------- Stripe attention ----------------
// grid = dim3(512, nb): x = dir(2) x stripe(64) x head(4); y = batch image.
// 256 threads = 256 queries (seq = stripe_w(2) * 128).
// qkv row layout: [rows][768]; q at dir*128+head*32, k at +256, v at +512.
__global__ __launch_bounds__(256) void attn_kernel(
        const bf16* __restrict__ qkv, bf16* __restrict__ h) {
    __shared__ float Ks[SEQ][HD];   // 32 KiB
    __shared__ float Vs[SEQ][HD];   // 32 KiB

    const int bid = blockIdx.x;
    const int head = bid & 3;
    const int s = (bid >> 2) & 63;
    const int dir = bid >> 8;
    const int b = blockIdx.y;

    const int t = threadIdx.x;          // query index in [0,256)
    const int al = t >> 7;              // position within stripe width (0/1)
    const int l = t & 127;
    int hpos, wpos;
    if (dir == 0) { hpos = 2 * s + al; wpos = l; }
    else          { wpos = 2 * s + al; hpos = l; }
    const size_t row = ((size_t)(b * 128 + hpos)) * 128 + wpos;
    const bf16* base = qkv + row * QKVN;
    const int qoff = dir * 128 + head * HD;

    float qv[HD];
    #pragma unroll
    for (int d8 = 0; d8 < HD; d8 += 8) load8f(base + qoff + d8, qv + d8);
    #pragma unroll
    for (int d8 = 0; d8 < HD; d8 += 8) load8f(base + 256 + qoff + d8, &Ks[t][d8]);
    #pragma unroll
    for (int d8 = 0; d8 < HD; d8 += 8) load8f(base + 512 + qoff + d8, &Vs[t][d8]);
    __syncthreads();

    const float scale = 0.17677669529663687f;   // 1/sqrt(32)
    float acc[HD] = {};
    float lsum = 0.0f;
    for (int j = 0; j < SEQ; j++) {
        float sdot = 0.0f;
        #pragma unroll
        for (int d = 0; d < HD; d++) sdot += qv[d] * Ks[j][d];
        const float p = __expf(sdot * scale);
        lsum += p;
        #pragma unroll
        for (int d = 0; d < HD; d++) acc[d] += p * Vs[j][d];
    }
    const float inv = 1.0f / lsum;

    bf16* outp = h + row * DIM + dir * 128 + head * HD;
    #pragma unroll
    for (int d8 = 0; d8 < HD; d8 += 8) {
        uint4 w;
        w.x = pack2(acc[d8 + 0] * inv, acc[d8 + 1] * inv);
        w.y = pack2(acc[d8 + 2] * inv, acc[d8 + 3] * inv);
        w.z = pack2(acc[d8 + 4] * inv, acc[d8 + 5] * inv);
        w.w = pack2(acc[d8 + 6] * inv, acc[d8 + 7] * inv);
        *reinterpret_cast<uint4*>(outp + d8) = w;
    }
}

extern "C" void kernel_launch(void* const* d_in, const int* in_sizes, int n_in,
                              void* d_out, int out_size, void* d_ws, size_t ws_size,
                              hipStream_t stream) {
    const void* x     = d_in[0];
    const void* Wqkv  = d_in[1];
    const void* bqkv  = d_in[2];
    const void* Wproj = d_in[3];
    const void* bproj = d_in[4];
    const void* gamma = d_in[5];
    const void* beta  = d_in[6];
    char* ws = (char*)d_ws;

    if (ws_size >= (size_t)268435456) {
        // Full path: xn/h (64 MiB, shared) + qkv (192 MiB) = 256 MiB
        bf16* xn_h = (bf16*)ws;
        bf16* qkv  = (bf16*)(ws + (size_t)NROWS * DIM * 2);
        ln_kernel<<<NROWS, 256, 0, stream>>>(x, gamma, beta, xn_h, 0);
        gemm_kernel<<<dim3(QKVN / BN, NROWS / BM), 256, 0, stream>>>(
            xn_h, Wqkv, bqkv, nullptr, 0, gamma, qkv, NROWS, QKVN, DIM, 0);
        attn_kernel<<<dim3(512, 8), 256, 0, stream>>>(qkv, xn_h);
        gemm_kernel<<<dim3(DIM / BN, NROWS / BM), 256, 0, stream>>>(
            xn_h, Wproj, bproj, x, 0, gamma, d_out, NROWS, DIM, DIM, 1);
    } else {
        // Per-image path: 8 chunks of 16384 rows; ws peak = 40 MiB
        // (chunk must be a full 128x128 image: vertical stripes span all h)
        const int MB = NROWS / 8;                       // 16384 rows per image
        bf16* xn_b  = (bf16*)ws;                        // 8 MiB
        bf16* qkv_b = (bf16*)(ws + (size_t)MB * DIM * 2);            // 24 MiB
        bf16* h_b   = (bf16*)(ws + (size_t)MB * (DIM + QKVN) * 2);   // 8 MiB
        for (int b = 0; b < 8; b++) {
            const size_t ro = (size_t)b * MB * DIM;     // element offset into x/out
            ln_kernel<<<MB, 256, 0, stream>>>(x, gamma, beta, xn_b, ro);
            gemm_kernel<<<dim3(QKVN / BN, MB / BM), 256, 0, stream>>>(
                xn_b, Wqkv, bqkv, nullptr, 0, gamma, qkv_b, MB, QKVN, DIM, 0);
            attn_kernel<<<dim3(512, 1), 256, 0, stream>>>(qkv_b, h_b);
            gemm_kernel<<<dim3(DIM / BN, MB / BM), 256, 0, stream>>>(
                h_b, Wproj, bproj, x, ro, gamma, (float*)d_out + ro, MB, DIM, DIM, 1);
        }
    }
}

// Round 4
// 1241.624 us; speedup vs baseline: 1.5766x; 1.5766x over previous
//
#include <hip/hip_runtime.h>
#include <hip/hip_bf16.h>

typedef __hip_bfloat16 bf16;
typedef unsigned short u16;
typedef unsigned int u32;
typedef __attribute__((ext_vector_type(8))) short short8;   // 8 x bf16 (4 VGPRs)
typedef __attribute__((ext_vector_type(4))) float floatx4;  // 4 x f32 acc

#define NROWS (8*128*128)   // 131072 spatial positions
#define DIM 256
#define QKVN 768
#define HD 32
#define SEQ 256             // stripe sequence length = sw(2) * 128

__device__ __forceinline__ float b2f_bits(u16 u) {
    union { float f; u32 i; } x; x.i = ((u32)u) << 16; return x.f;
}
__device__ __forceinline__ u16 f2b_bits(float f) {
    bf16 h = __float2bfloat16(f);
    return *reinterpret_cast<u16*>(&h);
}
__device__ __forceinline__ u32 pack2(float a, float b) {
    return ((u32)f2b_bits(b) << 16) | (u32)f2b_bits(a);
}
// load 8 consecutive bf16 (16B) -> 8 floats
__device__ __forceinline__ void load8f(const bf16* p, float* d) {
    uint4 w = *reinterpret_cast<const uint4*>(p);
    d[0] = b2f_bits((u16)(w.x & 0xffff)); d[1] = b2f_bits((u16)(w.x >> 16));
    d[2] = b2f_bits((u16)(w.y & 0xffff)); d[3] = b2f_bits((u16)(w.y >> 16));
    d[4] = b2f_bits((u16)(w.z & 0xffff)); d[5] = b2f_bits((u16)(w.z >> 16));
    d[6] = b2f_bits((u16)(w.w & 0xffff)); d[7] = b2f_bits((u16)(w.w >> 16));
}
// async global->LDS, 16B per lane (lds dest must be wave-uniform base + lane*16)
__device__ __forceinline__ void gload16(const void* g, void* l) {
    __builtin_amdgcn_global_load_lds(
        (const __attribute__((address_space(1))) void*)g,
        (__attribute__((address_space(3))) void*)l, 16, 0, 0);
}

// ---------------- Weight transpose+convert: W[k][n] f32 -> WT[n][k] bf16 ----
__global__ __launch_bounds__(256) void convert_kernel(
        const float* __restrict__ Wqkv, const float* __restrict__ Wproj,
        bf16* __restrict__ WTq, bf16* __restrict__ WTp) {
    const int n = blockIdx.x;
    const int k = threadIdx.x;
    if (n < QKVN) {
        WTq[(size_t)n * DIM + k] = __float2bfloat16(Wqkv[(size_t)k * QKVN + n]);
    } else {
        const int n2 = n - QKVN;
        WTp[(size_t)n2 * DIM + k] = __float2bfloat16(Wproj[(size_t)k * DIM + n2]);
    }
}

// ---------------- LayerNorm: one block (256 thr) per row ----------------
__global__ __launch_bounds__(256) void ln_kernel(
        const float* __restrict__ x, const float* __restrict__ gamma,
        const float* __restrict__ beta, bf16* __restrict__ xn, size_t x_off) {
    __shared__ float red[8];
    const int row = blockIdx.x;
    const int t = threadIdx.x;
    const size_t base = x_off + (size_t)row * DIM;
    float v = x[base + t];

    float s = v;
    #pragma unroll
    for (int off = 32; off > 0; off >>= 1) s += __shfl_down(s, off, 64);
    const int wave = t >> 6, lane = t & 63;
    if (lane == 0) red[wave] = s;
    __syncthreads();
    if (t == 0) red[4] = (red[0] + red[1] + red[2] + red[3]) * (1.0f / DIM);
    __syncthreads();
    const float mean = red[4];

    const float d = v - mean;
    s = d * d;
    #pragma unroll
    for (int off = 32; off > 0; off >>= 1) s += __shfl_down(s, off, 64);
    if (lane == 0) red[wave] = s;
    __syncthreads();
    if (t == 0) red[5] = rsqrtf((red[0] + red[1] + red[2] + red[3]) * (1.0f / DIM) + 1e-5f);
    __syncthreads();
    const float rstd = red[5];

    xn[(size_t)row * DIM + t] = __float2bfloat16(d * rstd * gamma[t] + beta[t]);
}

// ---------------- MFMA GEMM: C[M,N] = A[M,256] @ WT^T + bias (+resid) ------
// A: bf16 row-major [M][256]. WT: bf16 [N][256] (i.e. W transposed).
// 128x128 tile, BK=32, 4 waves in 2x2, each wave 4x4 mfma_f32_16x16x32_bf16.
// out_f32: f32 store + resid (final proj) vs bf16 store (qkv).
__global__ __launch_bounds__(256) void gemm_mfma(
        const bf16* __restrict__ A, const bf16* __restrict__ WT,
        const float* __restrict__ bias, const float* __restrict__ resid,
        void* __restrict__ Cout, int N, int out_f32) {
    __shared__ __align__(16) bf16 As[128][32];   // 8 KiB
    __shared__ __align__(16) bf16 Bs[128][32];   // 8 KiB

    const int tid = threadIdx.x;
    const int lane = tid & 63, wave = tid >> 6;
    const int wm = (wave >> 1) * 64, wn = (wave & 1) * 64;
    const int m = lane & 15, quad = lane >> 4;
    const int row0 = blockIdx.y * 128, col0 = blockIdx.x * 128;

    floatx4 acc[4][4] = {};

    // staging chunk ids: c covers 16B = 8 elems; row = c>>2, koff = (c&3)*8
    const int c0 = tid, c1 = tid + 256;
    const int r0_ = c0 >> 2, o0 = (c0 & 3) * 8;
    const int r1_ = c1 >> 2, o1 = (c1 & 3) * 8;

    for (int k0 = 0; k0 < DIM; k0 += 32) {
        __syncthreads();
        gload16(A  + (size_t)(row0 + r0_) * DIM + k0 + o0, (bf16*)As + c0 * 8);
        gload16(A  + (size_t)(row0 + r1_) * DIM + k0 + o1, (bf16*)As + c1 * 8);
        gload16(WT + (size_t)(col0 + r0_) * DIM + k0 + o0, (bf16*)Bs + c0 * 8);
        gload16(WT + (size_t)(col0 + r1_) * DIM + k0 + o1, (bf16*)Bs + c1 * 8);
        __syncthreads();

        short8 af[4], bfr[4];
        #pragma unroll
        for (int i = 0; i < 4; i++)
            af[i] = *reinterpret_cast<const short8*>(&As[wm + i * 16 + m][quad * 8]);
        #pragma unroll
        for (int j = 0; j < 4; j++)
            bfr[j] = *reinterpret_cast<const short8*>(&Bs[wn + j * 16 + m][quad * 8]);
        #pragma unroll
        for (int i = 0; i < 4; i++)
            #pragma unroll
            for (int j = 0; j < 4; j++)
                acc[i][j] = __builtin_amdgcn_mfma_f32_16x16x32_bf16(
                    af[i], bfr[j], acc[i][j], 0, 0, 0);
    }

    // epilogue: C/D layout col = lane&15, row = quad*4 + reg (m89-verified)
    #pragma unroll
    for (int j = 0; j < 4; j++) {
        const int col = col0 + wn + j * 16 + m;
        const float bj = bias[col];
        #pragma unroll
        for (int i = 0; i < 4; i++) {
            #pragma unroll
            for (int r = 0; r < 4; r++) {
                const int row = row0 + wm + i * 16 + quad * 4 + r;
                const float o = acc[i][j][r] + bj;
                if (out_f32) {
                    ((float*)Cout)[(size_t)row * N + col] =
                        o + resid[(size_t)row * N + col];
                } else {
                    ((bf16*)Cout)[(size_t)row * N + col] = __float2bfloat16(o);
                }
            }
        }
    }
}

// ---------------- Stripe attention (unchanged from round 3) ----------------
// grid = dim3(512, nb): x = dir(2) x stripe(64) x head(4); y = batch image.
__global__ __launch_bounds__(256) void attn_kernel(
        const bf16* __restrict__ qkv, bf16* __restrict__ h) {
    __shared__ float Ks[SEQ][HD];   // 32 KiB
    __shared__ float Vs[SEQ][HD];   // 32 KiB

    const int bid = blockIdx.x;
    const int head = bid & 3;
    const int s = (bid >> 2) & 63;
    const int dir = bid >> 8;
    const int b = blockIdx.y;

    const int t = threadIdx.x;          // query index in [0,256)
    const int al = t >> 7;              // position within stripe width (0/1)
    const int l = t & 127;
    int hpos, wpos;
    if (dir == 0) { hpos = 2 * s + al; wpos = l; }
    else          { wpos = 2 * s + al; hpos = l; }
    const size_t row = ((size_t)(b * 128 + hpos)) * 128 + wpos;
    const bf16* base = qkv + row * QKVN;
    const int qoff = dir * 128 + head * HD;

    float qv[HD];
    #pragma unroll
    for (int d8 = 0; d8 < HD; d8 += 8) load8f(base + qoff + d8, qv + d8);
    #pragma unroll
    for (int d8 = 0; d8 < HD; d8 += 8) load8f(base + 256 + qoff + d8, &Ks[t][d8]);
    #pragma unroll
    for (int d8 = 0; d8 < HD; d8 += 8) load8f(base + 512 + qoff + d8, &Vs[t][d8]);
    __syncthreads();

    const float scale = 0.17677669529663687f;   // 1/sqrt(32)
    float acc[HD] = {};
    float lsum = 0.0f;
    for (int j = 0; j < SEQ; j++) {
        float sdot = 0.0f;
        #pragma unroll
        for (int d = 0; d < HD; d++) sdot += qv[d] * Ks[j][d];
        const float p = __expf(sdot * scale);
        lsum += p;
        #pragma unroll
        for (int d = 0; d < HD; d++) acc[d] += p * Vs[j][d];
    }
    const float inv = 1.0f / lsum;

    bf16* outp = h + row * DIM + dir * 128 + head * HD;
    #pragma unroll
    for (int d8 = 0; d8 < HD; d8 += 8) {
        uint4 w;
        w.x = pack2(acc[d8 + 0] * inv, acc[d8 + 1] * inv);
        w.y = pack2(acc[d8 + 2] * inv, acc[d8 + 3] * inv);
        w.z = pack2(acc[d8 + 4] * inv, acc[d8 + 5] * inv);
        w.w = pack2(acc[d8 + 6] * inv, acc[d8 + 7] * inv);
        *reinterpret_cast<uint4*>(outp + d8) = w;
    }
}

extern "C" void kernel_launch(void* const* d_in, const int* in_sizes, int n_in,
                              void* d_out, int out_size, void* d_ws, size_t ws_size,
                              hipStream_t stream) {
    const float* x     = (const float*)d_in[0];
    const float* Wqkv  = (const float*)d_in[1];
    const float* bqkv  = (const float*)d_in[2];
    const float* Wproj = (const float*)d_in[3];
    const float* bproj = (const float*)d_in[4];
    const float* gamma = (const float*)d_in[5];
    const float* beta  = (const float*)d_in[6];
    char* ws = (char*)d_ws;

    const size_t MB256 = (size_t)268435456;
    if (ws_size >= MB256 + 524288) {
        // [0,64M): xn, later h   [64M,256M): qkv   [256M,+512K): WTq|WTp
        bf16* xn_h = (bf16*)ws;
        bf16* qkv  = (bf16*)(ws + (size_t)NROWS * DIM * 2);
        bf16* WTq  = (bf16*)(ws + MB256);
        bf16* WTp  = WTq + (size_t)QKVN * DIM;

        convert_kernel<<<QKVN + DIM, 256, 0, stream>>>(Wqkv, Wproj, WTq, WTp);
        ln_kernel<<<NROWS, 256, 0, stream>>>(x, gamma, beta, xn_h, 0);
        gemm_mfma<<<dim3(QKVN / 128, NROWS / 128), 256, 0, stream>>>(
            xn_h, WTq, bqkv, nullptr, qkv, QKVN, 0);
        attn_kernel<<<dim3(512, 8), 256, 0, stream>>>(qkv, xn_h);
        gemm_mfma<<<dim3(DIM / 128, NROWS / 128), 256, 0, stream>>>(
            xn_h, WTp, bproj, x, d_out, DIM, 1);
    } else {
        // Per-image path: WT @0 (512K), xn_b @1M (8M), qkv_b @9M (24M), h_b @33M (8M)
        const int MB = NROWS / 8;   // 16384 rows per image
        bf16* WTq   = (bf16*)ws;
        bf16* WTp   = WTq + (size_t)QKVN * DIM;
        bf16* xn_b  = (bf16*)(ws + (size_t)1048576);
        bf16* qkv_b = (bf16*)(ws + (size_t)9 * 1048576);
        bf16* h_b   = (bf16*)(ws + (size_t)33 * 1048576);

        convert_kernel<<<QKVN + DIM, 256, 0, stream>>>(Wqkv, Wproj, WTq, WTp);
        for (int b = 0; b < 8; b++) {
            const size_t ro = (size_t)b * MB * DIM;
            ln_kernel<<<MB, 256, 0, stream>>>(x, gamma, beta, xn_b, ro);
            gemm_mfma<<<dim3(QKVN / 128, MB / 128), 256, 0, stream>>>(
                xn_b, WTq, bqkv, nullptr, qkv_b, QKVN, 0);
            attn_kernel<<<dim3(512, 1), 256, 0, stream>>>(qkv_b, h_b);
            gemm_mfma<<<dim3(DIM / 128, MB / 128), 256, 0, stream>>>(
                h_b, WTp, bproj, x + ro, (float*)d_out + ro, DIM, 1);
        }
    }
}